// Round 11
// baseline (403.731 us; speedup 1.0000x reference)
//
#include <hip/hip_runtime.h>
#include <hip/hip_bf16.h>

typedef unsigned short u16;
typedef short bf16x8 __attribute__((ext_vector_type(8)));
typedef float f32x4 __attribute__((ext_vector_type(4)));
typedef unsigned int u32x4 __attribute__((ext_vector_type(4)));

__device__ __forceinline__ float bflo(unsigned u) { return __uint_as_float(u << 16); }
__device__ __forceinline__ float bfhi(unsigned u) { return __uint_as_float(u & 0xffff0000u); }
__device__ __forceinline__ u16 f2bf(float f) {
    unsigned u = __float_as_uint(f);
    return (u16)((u + 0x7fffu + ((u >> 16) & 1u)) >> 16);  // RNE
}

#define CHUNK 8192     // edges per block in pass A
#define BN 512         // nodes per bucket (bucket = c >> 9)

// ---- pass A1: per-block bucket histogram + fused W->bf16 transpose ----
__global__ __launch_bounds__(256) void hist_prep_kernel(const int* __restrict__ cols,
                                                        unsigned* __restrict__ hist,
                                                        int E, int nbuckets, int nblocksA,
                                                        const float* __restrict__ W1,
                                                        const float* __restrict__ W2,
                                                        u16* __restrict__ WT1,
                                                        u16* __restrict__ WT2) {
    int blk = blockIdx.x;
    if (blk >= nblocksA) {
        int t = (blk - nblocksA) * 256 + threadIdx.x;
        if (t < 128 * 128) {
            int n = t >> 7, k = t & 127;
            WT1[n * 128 + k] = f2bf(W1[k * 128 + n]);
        } else if (t < 128 * 128 + 64 * 128) {
            int i = t - 128 * 128;
            int n = i >> 7, k = i & 127;
            WT2[n * 128 + k] = f2bf(W2[k * 64 + n]);
        }
        return;
    }
    __shared__ unsigned h[256];
    int t = threadIdx.x;
    h[t] = 0;
    __syncthreads();
    int base = blk * CHUNK;
#pragma unroll
    for (int j = 0; j < CHUNK / 256; j++) {
        int i = base + j * 256 + t;
        if (i < E) atomicAdd(&h[((unsigned)cols[i]) >> 9], 1u);
    }
    __syncthreads();
    if (t < nbuckets) hist[blk * nbuckets + t] = h[t];
}

// ---- pass A2a: per-bucket prefix over blocks (one WG per bucket) ----
__global__ __launch_bounds__(256) void scanA1_kernel(unsigned* __restrict__ hist,
                                                     unsigned* __restrict__ totals,
                                                     int nblocksA, int nbuckets) {
    __shared__ unsigned s[256];
    int t = threadIdx.x, b = blockIdx.x;
    unsigned val = (t < nblocksA) ? hist[t * nbuckets + b] : 0u;
    s[t] = val;
    __syncthreads();
    for (int off = 1; off < 256; off <<= 1) {
        unsigned v = (t >= off) ? s[t - off] : 0u;
        __syncthreads();
        s[t] += v;
        __syncthreads();
    }
    if (t < nblocksA) hist[t * nbuckets + b] = s[t] - val;  // exclusive
    if (t == 255) totals[b] = s[255];
}

// ---- pass A2b: bucket bases (single WG) ----
__global__ __launch_bounds__(256) void scanA2_kernel(const unsigned* __restrict__ totals,
                                                     unsigned* __restrict__ bucketbase,
                                                     int nbuckets) {
    __shared__ unsigned s[256];
    int t = threadIdx.x;
    unsigned val = (t < nbuckets) ? totals[t] : 0u;
    s[t] = val;
    __syncthreads();
    for (int off = 1; off < 256; off <<= 1) {
        unsigned v = (t >= off) ? s[t - off] : 0u;
        __syncthreads();
        s[t] += v;
        __syncthreads();
    }
    unsigned ex = s[t] - val;
    if (t < nbuckets) bucketbase[t] = ex;
    if (t == nbuckets - 1) bucketbase[nbuckets] = ex + val;  // == E
}

// ---- pass A3: LDS-staged scatter -> coalesced bucket-group writes ----
__global__ __launch_bounds__(256) void scatterA_kernel(const int* __restrict__ rows,
                                                       const int* __restrict__ cols,
                                                       const unsigned* __restrict__ hist,
                                                       const unsigned* __restrict__ bucketbase,
                                                       uint2* __restrict__ binned,
                                                       int E, int nbuckets) {
    __shared__ uint2 sp[CHUNK];
    __shared__ unsigned lstart[256];
    __shared__ unsigned lcur[256];
    __shared__ unsigned gbase[256];
    int t = threadIdx.x, blk = blockIdx.x;
    int base = blk * CHUNK;
    int cnt = min(CHUNK, E - base);

    lcur[t] = 0;
    __syncthreads();
    for (int i = t; i < cnt; i += 256)
        atomicAdd(&lcur[((unsigned)cols[base + i]) >> 9], 1u);
    __syncthreads();
    unsigned val = lcur[t];
    lstart[t] = val;
    __syncthreads();
    for (int off = 1; off < 256; off <<= 1) {
        unsigned v = (t >= off) ? lstart[t - off] : 0u;
        __syncthreads();
        lstart[t] += v;
        __syncthreads();
    }
    unsigned ex = lstart[t] - val;
    __syncthreads();
    lstart[t] = ex;
    lcur[t] = ex;
    if (t < nbuckets) gbase[t] = bucketbase[t] + hist[blk * nbuckets + t];
    __syncthreads();
    for (int i = t; i < cnt; i += 256) {
        unsigned c = (unsigned)cols[base + i];
        unsigned r = (unsigned)rows[base + i];
        unsigned pos = atomicAdd(&lcur[c >> 9], 1u);
        sp[pos] = make_uint2(r, c);
    }
    __syncthreads();
    for (int i = t; i < cnt; i += 256) {
        uint2 u = sp[i];
        unsigned g = u.y >> 9;
        binned[gbase[g] + (unsigned)i - lstart[g]] = u;
    }
}

// ---- pass B: per bucket — local count/scan -> rowptr, dinv, srcidx ----
__global__ __launch_bounds__(256) void binB_kernel(const uint2* __restrict__ binned,
                                                   const unsigned* __restrict__ bucketbase,
                                                   int* __restrict__ rowptr,
                                                   float* __restrict__ dinv,
                                                   int* __restrict__ srcidx,
                                                   int N, int E, int nbuckets) {
    __shared__ unsigned cnt[BN + 1];
    __shared__ unsigned sc[BN + 1];
    __shared__ unsigned ps[256];
    int t = threadIdx.x, b = blockIdx.x;
    int lo = b << 9;
    int nn = min(BN, N - lo);
    unsigned s = bucketbase[b], e = bucketbase[b + 1];

    cnt[t] = 0;
    cnt[t + 256] = 0;
    if (t == 0) cnt[BN] = 0;
    __syncthreads();
    for (unsigned i = s + t; i < e; i += 256)
        atomicAdd(&cnt[binned[i].y - lo], 1u);
    __syncthreads();

    unsigned a0 = cnt[2 * t], a1 = cnt[2 * t + 1];
    ps[t] = a0 + a1;
    __syncthreads();
    unsigned val = ps[t];
    for (int off = 1; off < 256; off <<= 1) {
        unsigned v = (t >= off) ? ps[t - off] : 0u;
        __syncthreads();
        ps[t] += v;
        __syncthreads();
    }
    unsigned ex = ps[t] - val;
    sc[2 * t] = ex;
    sc[2 * t + 1] = ex + a0;
    if (t == 255) sc[BN] = ex + val;
    __syncthreads();

    for (int n = t; n < nn; n += 256) {
        unsigned rp = s + sc[n];
        rowptr[lo + n] = (int)rp;
        dinv[lo + n] = rsqrtf((float)(sc[n + 1] - sc[n]) + 1.0f);
        cnt[n] = rp;
    }
    if (b == nbuckets - 1 && t == 0) rowptr[N] = E;
    __syncthreads();

    for (unsigned i = s + t; i < e; i += 256) {
        uint2 u = binned[i];
        unsigned slot = atomicAdd(&cnt[u.y - lo], 1u);
        srcidx[slot] = (int)u.x;
    }
}

// ---- layer-1 MFMA GEMM: x (fp32 [N][128]) @ W1 -> h1t tiled [8][N][16] bf16, *dinv ----
__global__ __launch_bounds__(256) void gemm1_mfma(const float* __restrict__ X,
                                                  const u16* __restrict__ WT,  // [128][128]
                                                  const float* __restrict__ dinv,
                                                  u16* __restrict__ h1t, int N) {
    constexpr int LDK = 136;
    __shared__ u16 sX[64 * LDK];
    __shared__ u16 sW[128 * LDK];

    const int t = threadIdx.x;
    const int wv = t >> 6, lane = t & 63;
    const int m = lane & 15, q = lane >> 4;
    const int row0 = blockIdx.x * 64;

    for (int idx = t; idx < 128 * 16; idx += 256) {
        int n = idx >> 4, c = idx & 15;
        *((uint4*)&sW[n * LDK + c * 8]) = ((const uint4*)WT)[idx];
    }
    for (int idx = t; idx < 64 * 32; idx += 256) {
        int r = idx >> 5, c = idx & 31;
        int gr = row0 + r;
        float4 v = make_float4(0.f, 0.f, 0.f, 0.f);
        if (gr < N) v = ((const float4*)X)[(size_t)gr * 32 + c];
        uint2 o;
        o.x = (unsigned)f2bf(v.x) | ((unsigned)f2bf(v.y) << 16);
        o.y = (unsigned)f2bf(v.z) | ((unsigned)f2bf(v.w) << 16);
        *((uint2*)&sX[r * LDK + c * 4]) = o;
    }
    __syncthreads();

    f32x4 acc[8];
#pragma unroll
    for (int i = 0; i < 8; i++) acc[i] = (f32x4){0.f, 0.f, 0.f, 0.f};

#pragma unroll
    for (int ks = 0; ks < 4; ks++) {
        const int k0 = ks * 32 + q * 8;
        bf16x8 a = *((const bf16x8*)&sX[(wv * 16 + m) * LDK + k0]);
#pragma unroll
        for (int nt = 0; nt < 8; nt++) {
            bf16x8 b = *((const bf16x8*)&sW[(nt * 16 + m) * LDK + k0]);
            acc[nt] = __builtin_amdgcn_mfma_f32_16x16x32_bf16(a, b, acc[nt], 0, 0, 0);
        }
    }

#pragma unroll
    for (int r = 0; r < 4; r++) {
        int gi = row0 + wv * 16 + q * 4 + r;
        if (gi < N) {
            float dv = dinv[gi];
#pragma unroll
            for (int nt = 0; nt < 8; nt++) {
                h1t[((size_t)nt * N + gi) * 16 + m] = f2bf(acc[nt][r] * dv);
            }
        }
    }
}

// ---- layer-2 MFMA GEMM: h1a tiled [8][N][16] bf16 @ W2 -> h2t tiled [4][N][16], *dinv ----
__global__ __launch_bounds__(256) void gemm2_mfma(const u16* __restrict__ h1a,
                                                  const u16* __restrict__ WT,  // [64][128]
                                                  const float* __restrict__ dinv,
                                                  u16* __restrict__ h2t, int N) {
    constexpr int LDK = 136;
    __shared__ u16 sX[64 * LDK];
    __shared__ u16 sW[64 * LDK];

    const int t = threadIdx.x;
    const int wv = t >> 6, lane = t & 63;
    const int m = lane & 15, q = lane >> 4;
    const int row0 = blockIdx.x * 64;

    for (int idx = t; idx < 64 * 16; idx += 256) {
        int n = idx >> 4, c = idx & 15;
        *((uint4*)&sW[n * LDK + c * 8]) = ((const uint4*)WT)[idx];
    }
    // stage X from tiled layout: slab s, row r, piece p (8 feats per uint4)
    for (int idx = t; idx < 1024; idx += 256) {
        int p = idx & 1, r = (idx >> 1) & 63, s = idx >> 7;
        int gr = row0 + r;
        uint4 v = make_uint4(0u, 0u, 0u, 0u);
        if (gr < N) v = ((const uint4*)h1a)[((size_t)s * N + gr) * 2 + p];
        *((uint4*)&sX[r * LDK + s * 16 + p * 8]) = v;
    }
    __syncthreads();

    f32x4 acc[4];
#pragma unroll
    for (int i = 0; i < 4; i++) acc[i] = (f32x4){0.f, 0.f, 0.f, 0.f};

#pragma unroll
    for (int ks = 0; ks < 4; ks++) {
        const int k0 = ks * 32 + q * 8;
        bf16x8 a = *((const bf16x8*)&sX[(wv * 16 + m) * LDK + k0]);
#pragma unroll
        for (int nt = 0; nt < 4; nt++) {
            bf16x8 b = *((const bf16x8*)&sW[(nt * 16 + m) * LDK + k0]);
            acc[nt] = __builtin_amdgcn_mfma_f32_16x16x32_bf16(a, b, acc[nt], 0, 0, 0);
        }
    }

#pragma unroll
    for (int r = 0; r < 4; r++) {
        int gi = row0 + wv * 16 + q * 4 + r;
        if (gi < N) {
            float dv = dinv[gi];
#pragma unroll
            for (int nt = 0; nt < 4; nt++) {
                h2t[((size_t)nt * N + gi) * 16 + m] = f2bf(acc[nt][r] * dv);
            }
        }
    }
}

// ---- feature-sliced aggregate, layer 1: slab fb = blockIdx%8 (XCD-affine) ----
__global__ __launch_bounds__(256) void agg1_kernel(const int* __restrict__ rowptr,
                                                   const int* __restrict__ srcidx,
                                                   const u16* __restrict__ h1t,
                                                   const float* __restrict__ dinv,
                                                   const float* __restrict__ b1,
                                                   u16* __restrict__ h1a, int N) {
    int fb = blockIdx.x & 7;
    int node = (blockIdx.x >> 3) * 256 + threadIdx.x;
    if (node >= N) return;
    const uint4* H = (const uint4*)h1t + (size_t)fb * N * 2;

    float a[16];
    {
        uint4 u0 = H[node * 2], u1 = H[node * 2 + 1];
        a[0] = bflo(u0.x); a[1] = bfhi(u0.x); a[2] = bflo(u0.y); a[3] = bfhi(u0.y);
        a[4] = bflo(u0.z); a[5] = bfhi(u0.z); a[6] = bflo(u0.w); a[7] = bfhi(u0.w);
        a[8] = bflo(u1.x); a[9] = bfhi(u1.x); a[10] = bflo(u1.y); a[11] = bfhi(u1.y);
        a[12] = bflo(u1.z); a[13] = bfhi(u1.z); a[14] = bflo(u1.w); a[15] = bfhi(u1.w);
    }
    int start = rowptr[node], end = rowptr[node + 1];
    int nfull = (end - start) >> 2;
    int i = start;
    int r[4], r2[4];
    if (nfull > 0) {
#pragma unroll
        for (int j = 0; j < 4; j++) r[j] = __builtin_nontemporal_load(&srcidx[i + j]);
    }
    for (int b = 0; b < nfull; b++) {
        uint4 u0[4], u1[4];
#pragma unroll
        for (int j = 0; j < 4; j++) { u0[j] = H[r[j] * 2]; u1[j] = H[r[j] * 2 + 1]; }
        if (b + 1 < nfull) {
#pragma unroll
            for (int j = 0; j < 4; j++) r2[j] = __builtin_nontemporal_load(&srcidx[i + 4 + j]);
        }
#pragma unroll
        for (int j = 0; j < 4; j++) {
            a[0] += bflo(u0[j].x); a[1] += bfhi(u0[j].x); a[2] += bflo(u0[j].y); a[3] += bfhi(u0[j].y);
            a[4] += bflo(u0[j].z); a[5] += bfhi(u0[j].z); a[6] += bflo(u0[j].w); a[7] += bfhi(u0[j].w);
            a[8] += bflo(u1[j].x); a[9] += bfhi(u1[j].x); a[10] += bflo(u1[j].y); a[11] += bfhi(u1[j].y);
            a[12] += bflo(u1[j].z); a[13] += bfhi(u1[j].z); a[14] += bflo(u1[j].w); a[15] += bfhi(u1[j].w);
        }
#pragma unroll
        for (int j = 0; j < 4; j++) r[j] = r2[j];
        i += 4;
    }
    for (; i < end; ++i) {
        int rr = __builtin_nontemporal_load(&srcidx[i]);
        uint4 u0 = H[rr * 2], u1 = H[rr * 2 + 1];
        a[0] += bflo(u0.x); a[1] += bfhi(u0.x); a[2] += bflo(u0.y); a[3] += bfhi(u0.y);
        a[4] += bflo(u0.z); a[5] += bfhi(u0.z); a[6] += bflo(u0.w); a[7] += bfhi(u0.w);
        a[8] += bflo(u1.x); a[9] += bfhi(u1.x); a[10] += bflo(u1.y); a[11] += bfhi(u1.y);
        a[12] += bflo(u1.z); a[13] += bfhi(u1.z); a[14] += bflo(u1.w); a[15] += bfhi(u1.w);
    }

    float dv = dinv[node];
    const float* bp = b1 + fb * 16;
    u16 pk[16];
#pragma unroll
    for (int j = 0; j < 16; j++) pk[j] = f2bf(fmaxf(dv * a[j] + bp[j], 0.f));
    u32x4 w0, w1;
    w0[0] = pk[0] | ((unsigned)pk[1] << 16);  w0[1] = pk[2] | ((unsigned)pk[3] << 16);
    w0[2] = pk[4] | ((unsigned)pk[5] << 16);  w0[3] = pk[6] | ((unsigned)pk[7] << 16);
    w1[0] = pk[8] | ((unsigned)pk[9] << 16);  w1[1] = pk[10] | ((unsigned)pk[11] << 16);
    w1[2] = pk[12] | ((unsigned)pk[13] << 16); w1[3] = pk[14] | ((unsigned)pk[15] << 16);
    u32x4* O = (u32x4*)((uint4*)h1a + (size_t)fb * N * 2);
    __builtin_nontemporal_store(w0, &O[node * 2]);
    __builtin_nontemporal_store(w1, &O[node * 2 + 1]);
}

// ---- feature-sliced aggregate, layer 2: slab fb = blockIdx%4; fp32 out [N][64] ----
__global__ __launch_bounds__(256) void agg2_kernel(const int* __restrict__ rowptr,
                                                   const int* __restrict__ srcidx,
                                                   const u16* __restrict__ h2t,
                                                   const float* __restrict__ dinv,
                                                   const float* __restrict__ b2,
                                                   float* __restrict__ out, int N) {
    int fb = blockIdx.x & 3;
    int node = (blockIdx.x >> 2) * 256 + threadIdx.x;
    if (node >= N) return;
    const uint4* H = (const uint4*)h2t + (size_t)fb * N * 2;

    float a[16];
    {
        uint4 u0 = H[node * 2], u1 = H[node * 2 + 1];
        a[0] = bflo(u0.x); a[1] = bfhi(u0.x); a[2] = bflo(u0.y); a[3] = bfhi(u0.y);
        a[4] = bflo(u0.z); a[5] = bfhi(u0.z); a[6] = bflo(u0.w); a[7] = bfhi(u0.w);
        a[8] = bflo(u1.x); a[9] = bfhi(u1.x); a[10] = bflo(u1.y); a[11] = bfhi(u1.y);
        a[12] = bflo(u1.z); a[13] = bfhi(u1.z); a[14] = bflo(u1.w); a[15] = bfhi(u1.w);
    }
    int start = rowptr[node], end = rowptr[node + 1];
    int nfull = (end - start) >> 2;
    int i = start;
    int r[4], r2[4];
    if (nfull > 0) {
#pragma unroll
        for (int j = 0; j < 4; j++) r[j] = __builtin_nontemporal_load(&srcidx[i + j]);
    }
    for (int b = 0; b < nfull; b++) {
        uint4 u0[4], u1[4];
#pragma unroll
        for (int j = 0; j < 4; j++) { u0[j] = H[r[j] * 2]; u1[j] = H[r[j] * 2 + 1]; }
        if (b + 1 < nfull) {
#pragma unroll
            for (int j = 0; j < 4; j++) r2[j] = __builtin_nontemporal_load(&srcidx[i + 4 + j]);
        }
#pragma unroll
        for (int j = 0; j < 4; j++) {
            a[0] += bflo(u0[j].x); a[1] += bfhi(u0[j].x); a[2] += bflo(u0[j].y); a[3] += bfhi(u0[j].y);
            a[4] += bflo(u0[j].z); a[5] += bfhi(u0[j].z); a[6] += bflo(u0[j].w); a[7] += bfhi(u0[j].w);
            a[8] += bflo(u1[j].x); a[9] += bfhi(u1[j].x); a[10] += bflo(u1[j].y); a[11] += bfhi(u1[j].y);
            a[12] += bflo(u1[j].z); a[13] += bfhi(u1[j].z); a[14] += bflo(u1[j].w); a[15] += bfhi(u1[j].w);
        }
#pragma unroll
        for (int j = 0; j < 4; j++) r[j] = r2[j];
        i += 4;
    }
    for (; i < end; ++i) {
        int rr = __builtin_nontemporal_load(&srcidx[i]);
        uint4 u0 = H[rr * 2], u1 = H[rr * 2 + 1];
        a[0] += bflo(u0.x); a[1] += bfhi(u0.x); a[2] += bflo(u0.y); a[3] += bfhi(u0.y);
        a[4] += bflo(u0.z); a[5] += bfhi(u0.z); a[6] += bflo(u0.w); a[7] += bfhi(u0.w);
        a[8] += bflo(u1.x); a[9] += bfhi(u1.x); a[10] += bflo(u1.y); a[11] += bfhi(u1.y);
        a[12] += bflo(u1.z); a[13] += bfhi(u1.z); a[14] += bflo(u1.w); a[15] += bfhi(u1.w);
    }

    float dv = dinv[node];
    const float* bp = b2 + fb * 16;
    float* op = out + (size_t)node * 64 + fb * 16;
#pragma unroll
    for (int j4 = 0; j4 < 4; j4++) {
        f32x4 o;
        o[0] = dv * a[j4 * 4 + 0] + bp[j4 * 4 + 0];
        o[1] = dv * a[j4 * 4 + 1] + bp[j4 * 4 + 1];
        o[2] = dv * a[j4 * 4 + 2] + bp[j4 * 4 + 2];
        o[3] = dv * a[j4 * 4 + 3] + bp[j4 * 4 + 3];
        __builtin_nontemporal_store(o, (f32x4*)(op + j4 * 4));
    }
}

extern "C" void kernel_launch(void* const* d_in, const int* in_sizes, int n_in,
                              void* d_out, int out_size, void* d_ws, size_t ws_size,
                              hipStream_t stream) {
    const float* x  = (const float*)d_in[0];
    const int*   ei = (const int*)d_in[1];
    const float* W1 = (const float*)d_in[2];
    const float* b1 = (const float*)d_in[3];
    const float* W2 = (const float*)d_in[4];
    const float* b2 = (const float*)d_in[5];

    const int N = in_sizes[0] / 128;
    const int E = in_sizes[1] / 2;
    const int* rows = ei;
    const int* cols = ei + E;

    const int nbuckets = (N + BN - 1) / BN;          // 196 (<=256)
    const int nblocksA = (E + CHUNK - 1) / CHUNK;    // 196 (<=256)
    const int ngroups  = (N + 255) / 256;            // 391

    char* ws = (char*)d_ws;
    size_t off = 0;
    auto alloc = [&](size_t bytes) -> void* {
        void* p = ws + off;
        off = (off + bytes + 1023) & ~(size_t)1023;
        return p;
    };
    unsigned* hist       = (unsigned*)alloc((size_t)nbuckets * nblocksA * 4);
    unsigned* totals     = (unsigned*)alloc(256 * 4);
    unsigned* bucketbase = (unsigned*)alloc((size_t)(nbuckets + 1) * 4);
    uint2*    binned     = (uint2*)alloc((size_t)E * 8);
    int*      rowptr     = (int*)alloc((size_t)(N + 1) * 4);
    float*    dinv       = (float*)alloc((size_t)N * 4);
    int*      srcidx     = (int*)alloc((size_t)E * 4);
    u16*      WT1        = (u16*)alloc((size_t)128 * 128 * 2);
    u16*      WT2        = (u16*)alloc((size_t)64 * 128 * 2);
    u16*      h1t        = (u16*)alloc((size_t)N * 128 * 2);  // tiled [8][N][16]
    u16*      h1a        = (u16*)alloc((size_t)N * 128 * 2);  // tiled [8][N][16]
    u16*      h2t        = (u16*)alloc((size_t)N * 64 * 2);   // tiled [4][N][16]

    // CSR build + weight prep
    hist_prep_kernel<<<nblocksA + 96, 256, 0, stream>>>(cols, hist, E, nbuckets, nblocksA,
                                                        W1, W2, WT1, WT2);
    scanA1_kernel<<<nbuckets, 256, 0, stream>>>(hist, totals, nblocksA, nbuckets);
    scanA2_kernel<<<1, 256, 0, stream>>>(totals, bucketbase, nbuckets);
    scatterA_kernel<<<nblocksA, 256, 0, stream>>>(rows, cols, hist, bucketbase, binned, E, nbuckets);
    binB_kernel<<<nbuckets, 256, 0, stream>>>(binned, bucketbase, rowptr, dinv, srcidx, N, E, nbuckets);

    // layer 1
    gemm1_mfma<<<(N + 63) / 64, 256, 0, stream>>>(x, WT1, dinv, h1t, N);
    agg1_kernel<<<8 * ngroups, 256, 0, stream>>>(rowptr, srcidx, h1t, dinv, b1, h1a, N);

    // layer 2
    gemm2_mfma<<<(N + 63) / 64, 256, 0, stream>>>(h1a, WT2, dinv, h2t, N);
    agg2_kernel<<<4 * ngroups, 256, 0, stream>>>(rowptr, srcidx, h2t, dinv, b2, (float*)d_out, N);
}